// Round 10
// baseline (151.942 us; speedup 1.0000x reference)
//
#include <hip/hip_runtime.h>
#include <stdint.h>

// Problem constants
#define S_LEN 2048
#define D_DIM 1024
#define NB 2
#define NH 16
#define NE 64
#define N_COLS (3 * NH * NE)  // 3072 (Q | K | V column blocks)
#define K_DIM D_DIM           // 1024

typedef unsigned short u16;
typedef unsigned int u32;
typedef u16 u16x8 __attribute__((ext_vector_type(8)));
typedef __bf16 bf16x8 __attribute__((ext_vector_type(8)));
typedef float f32x4 __attribute__((ext_vector_type(4)));
typedef float f32x16 __attribute__((ext_vector_type(16)));

__device__ __forceinline__ u16 f2b(float f) {
  u32 u = __builtin_bit_cast(u32, f);
  return (u16)((u + 0x7FFFu + ((u >> 16) & 1u)) >> 16);  // RNE
}

__device__ __forceinline__ void gload_lds16(const void* g, void* l) {
  __builtin_amdgcn_global_load_lds(
      (const __attribute__((address_space(1))) u32*)g,
      (__attribute__((address_space(3))) u32*)l, 16, 0, 0);
}

// ---------- merged prep: blocks [0,2048) convert x; [2048,2816) transpose W ----------
__global__ __launch_bounds__(256) void k_prep(const float* __restrict__ x,
                                              const float* __restrict__ Wq,
                                              const float* __restrict__ Wk,
                                              const float* __restrict__ Wv,
                                              u16* __restrict__ xb,
                                              u16* __restrict__ Wt) {
  __shared__ u16 tile[64][65];
  int bid = blockIdx.x;
  int t = threadIdx.x;
  if (bid < 2048) {
    size_t i = (size_t)bid * 256 + t;
    const float4* xf = (const float4*)x;
    float4 a = xf[2 * i], c = xf[2 * i + 1];
    u16x8 o;
    o[0] = f2b(a.x); o[1] = f2b(a.y); o[2] = f2b(a.z); o[3] = f2b(a.w);
    o[4] = f2b(c.x); o[5] = f2b(c.y); o[6] = f2b(c.z); o[7] = f2b(c.w);
    *(u16x8*)(xb + 8 * i) = o;
  } else {
    int wbid = bid - 2048;             // proj*256 + h*16 + kb
    int kb = wbid & 15;
    int h = (wbid >> 4) & 15;
    int proj = wbid >> 8;
    const float* W = (proj == 0) ? Wq : ((proj == 1) ? Wk : Wv);
    int k0 = kb * 64;
    int e = t & 63, kr = t >> 6;
    const float* src = W + ((size_t)h * D_DIM + k0 + kr * 16) * NE + e;
#pragma unroll
    for (int j = 0; j < 16; ++j) tile[kr * 16 + j][e] = f2b(src[(size_t)j * NE]);
    __syncthreads();
    int e2 = t >> 2, kc = (t & 3) * 16;
    u16x8 o0, o1;
#pragma unroll
    for (int j = 0; j < 8; ++j) { o0[j] = tile[kc + j][e2]; o1[j] = tile[kc + 8 + j][e2]; }
    size_t n = (size_t)proj * 1024 + h * 64 + e2;
    u16* dst = Wt + n * K_DIM + k0 + kc;
    *(u16x8*)dst = o0;
    *(u16x8*)(dst + 8) = o1;
  }
}

// ------------- GEMM: qkv[4096,3072] = xb[4096,1024] @ Wt[3072,1024]^T -------------
__global__ __launch_bounds__(256) void k_gemm(const u16* __restrict__ A,
                                              const u16* __restrict__ Bt,
                                              u16* __restrict__ C) {
  __shared__ __align__(16) u16 As[128 * 64];
  __shared__ __align__(16) u16 Bs[128 * 64];
  int t = threadIdx.x;
  int lane = t & 63, w = t >> 6;
  int wr = (w >> 1) * 64, wc = (w & 1) * 64;
  int bid = blockIdx.x;
  int xcd = bid & 7, r0 = bid >> 3;          // r0 in [0,96)
  int m0 = (r0 / 3) * 128;
  int n0 = (xcd * 3 + (r0 % 3)) * 128;
  float qscale = ((n0 + wc) < 1024) ? 0.18033688f : 1.0f;  // 0.125*log2e
  f32x4 acc[4][4];
#pragma unroll
  for (int m = 0; m < 4; m++)
#pragma unroll
    for (int n = 0; n < 4; n++)
#pragma unroll
      for (int j = 0; j < 4; j++) acc[m][n][j] = 0.f;

  for (int k0 = 0; k0 < K_DIM; k0 += 64) {
#pragma unroll
    for (int i = 0; i < 4; ++i) {
      int ci = i * 256 + t;
      int row = ci >> 3, c = ci & 7;
      int cs = c ^ (row & 7);
      gload_lds16(A + (size_t)(m0 + row) * K_DIM + k0 + cs * 8,
                  (char*)As + (size_t)(i * 256 + w * 64) * 16);
      gload_lds16(Bt + (size_t)(n0 + row) * K_DIM + k0 + cs * 8,
                  (char*)Bs + (size_t)(i * 256 + w * 64) * 16);
    }
    __syncthreads();
#pragma unroll
    for (int ks = 0; ks < 2; ++ks) {
      int kc = ks * 4 + (lane >> 4);
      bf16x8 af[4], bfr[4];
#pragma unroll
      for (int m = 0; m < 4; m++) {
        int r = wr + m * 16 + (lane & 15);
        af[m] = *(const bf16x8*)&As[r * 64 + ((kc ^ (r & 7)) * 8)];
      }
#pragma unroll
      for (int n = 0; n < 4; n++) {
        int r = wc + n * 16 + (lane & 15);
        bfr[n] = *(const bf16x8*)&Bs[r * 64 + ((kc ^ (r & 7)) * 8)];
      }
#pragma unroll
      for (int m = 0; m < 4; m++)
#pragma unroll
        for (int n = 0; n < 4; n++)
          acc[m][n] = __builtin_amdgcn_mfma_f32_16x16x32_bf16(af[m], bfr[n], acc[m][n], 0, 0, 0);
    }
    __syncthreads();
  }
#pragma unroll
  for (int m = 0; m < 4; m++) {
#pragma unroll
    for (int r = 0; r < 4; r++) {
      int row = m0 + wr + m * 16 + (lane >> 4) * 4 + r;
#pragma unroll
      for (int n = 0; n < 4; n++) {
        int col = n0 + wc + n * 16 + (lane & 15);
        C[(size_t)row * N_COLS + col] = f2b(acc[m][n][r] * qscale);
      }
    }
  }
}

// ---- attention helpers (256-thread block) ----
__device__ __forceinline__ void stage_k(const u16* kb_, u16* kdst, int kv0, int t) {
#pragma unroll
  for (int i = 0; i < 2; ++i) {
    int ci = i * 256 + t;
    int row = ci >> 3, c = ci & 7;
    int cs = c ^ (row & 7);
    gload_lds16(kb_ + (size_t)(kv0 + row) * N_COLS + cs * 8,
                (char*)kdst + (size_t)ci * 16);
  }
}

// V write: thread covers kv pair vp = t>>3, e-chunk vec = t&7.
// Vt element (e,kv) at byte e*128 + slot*16 + (kv&7)*2, slot=(kv>>3)^(e&7)^(e>>3).
__device__ __forceinline__ void vwrite(u16* vt, u16x8 va, u16x8 vb2, int vp, int vec) {
#pragma unroll
  for (int j = 0; j < 8; ++j) {
    int e = vec * 8 + j;
    int slot = (vp >> 2) ^ (e & 7) ^ (e >> 3);
    *(u32*)((char*)vt + e * 128 + slot * 16 + (vp & 3) * 4) =
        (u32)va[j] | ((u32)vb2[j] << 16);
  }
}

// ------- flash attention, causal, 32x32 MFMA, QBLK=128, 4 waves x 32 q-rows -------
// 512 blocks; decode: xcd=bid&7, g=bid>>3; bh=xcd*4+(g&3) (4 heads/XCD L2);
// qb=15-(g>>2) (LPT). Wave w owns q-rows [q0+32w, q0+32w+32). nt=2qb+2 kv-tiles.
// Per-wave uniform skip when tile fully masked; per-element mask only when
// kv0+63 > wave q-base. 32x32x16 layouts: A/B lane: row|col=lane&31,
// k=(lane>>5)*8+j. C/D: col=lane&31, row=(reg&3)+8*(reg>>2)+4*(lane>>5) (m74).
// No-max exp2 softmax (Q pre-scaled in GEMM); lrow[16] per lane, reduced at end.
__global__ __launch_bounds__(256, 3) void k_attn(const u16* __restrict__ qkv,
                                                 float* __restrict__ out) {
  __shared__ __align__(16) u16 Ks[2][64 * 64];
  __shared__ __align__(16) u16 Vt[2][64 * 64];
  __shared__ __align__(16) u16 Ps[4][32 * 64];
  int t = threadIdx.x;
  int lane = t & 63, w = t >> 6;
  int half = lane >> 5, l31 = lane & 31;
  int bid = blockIdx.x;                 // 0..511
  int xcd = bid & 7, g = bid >> 3;
  int bh = xcd * 4 + (g & 3);
  int qb = 15 - (g >> 2);
  int b = bh >> 4, h = bh & 15;
  const u16* qb_ = qkv + (size_t)b * S_LEN * N_COLS + h * NE;
  const u16* kb_ = qb_ + 1024;
  const u16* vb_ = qb_ + 2048;
  int vp = t >> 3, vec = t & 7;

  int q0 = qb * 128;
  int nt = 2 * qb + 2;
  int wqb = q0 + w * 32;                // wave q base

  // Q fragments: lane holds Q[wqb + l31][ks*16 + half*8 + 0..7], ks=0..3
  bf16x8 qf[4];
#pragma unroll
  for (int ks = 0; ks < 4; ks++)
    qf[ks] = *(const bf16x8*)(qb_ + (size_t)(wqb + l31) * N_COLS + ks * 16 + half * 8);

  f32x16 o[2];
  float lrow[16];
#pragma unroll
  for (int n2 = 0; n2 < 2; n2++)
#pragma unroll
    for (int r = 0; r < 16; r++) o[n2][r] = 0.f;
#pragma unroll
  for (int r = 0; r < 16; r++) lrow[r] = 0.f;

  // prologue: stage tile 0 into buffer 0
  stage_k(kb_, Ks[0], 0, t);
  {
    const u16* vs = vb_ + (size_t)(2 * vp) * N_COLS + vec * 8;
    u16x8 va = *(const u16x8*)vs;
    u16x8 vb2 = *(const u16x8*)(vs + N_COLS);
    vwrite(Vt[0], va, vb2, vp, vec);
  }
  __syncthreads();

  int cur = 0;
  for (int ti = 0; ti < nt; ++ti) {
    int kv0 = ti * 64;
    bool pf = (ti + 1 < nt);
    u16x8 va, vb2;
    if (pf) {
      const u16* vs = vb_ + (size_t)(kv0 + 64 + 2 * vp) * N_COLS + vec * 8;
      va = *(const u16x8*)vs;            // in flight during QK^T+softmax
      vb2 = *(const u16x8*)(vs + N_COLS);
      stage_k(kb_, Ks[cur ^ 1], kv0 + 64, t);
    }

    bool doWork = (kv0 <= wqb + 31);     // wave-uniform: any unmasked element?
    bool needMask = (kv0 + 63 > wqb);    // wave-uniform: any masked element?

    if (doWork) {
      // S = Q K^T : D[q][kv], 2 n-tiles x 4 k-steps of 32x32x16
      f32x16 s[2];
#pragma unroll
      for (int n2 = 0; n2 < 2; n2++)
#pragma unroll
        for (int r = 0; r < 16; r++) s[n2][r] = 0.f;
      __builtin_amdgcn_s_setprio(1);
#pragma unroll
      for (int ks = 0; ks < 4; ks++) {
#pragma unroll
        for (int n2 = 0; n2 < 2; n2++) {
          int kr = n2 * 32 + l31;                       // kv row in Ks
          int c = (ks * 2 + half) ^ (kr & 7);           // swizzled 16B chunk
          bf16x8 kf = *(const bf16x8*)&Ks[cur][kr * 64 + c * 8];
          s[n2] = __builtin_amdgcn_mfma_f32_32x32x16_bf16(qf[ks], kf, s[n2], 0, 0, 0);
        }
      }
      __builtin_amdgcn_s_setprio(0);

      // softmax: p = exp2(s); mask last tiles per-element; accumulate lrow.
#pragma unroll
      for (int r = 0; r < 16; r++) {
        int rowq = (r & 3) + 8 * (r >> 2) + 4 * half;   // q offset within wave
#pragma unroll
        for (int n2 = 0; n2 < 2; n2++) {
          float p = __builtin_amdgcn_exp2f(s[n2][r]);
          if (needMask) {
            int kv = kv0 + n2 * 32 + l31;
            p = (kv <= wqb + rowq) ? p : 0.f;
          }
          s[n2][r] = p;
          lrow[r] += p;
        }
      }

      // P -> LDS bf16 (own-wave region, swizzled like Ks)
#pragma unroll
      for (int r = 0; r < 16; r++) {
        int row = (r & 3) + 8 * (r >> 2) + 4 * half;
#pragma unroll
        for (int n2 = 0; n2 < 2; n2++) {
          int col = n2 * 32 + l31;
          int swz = (col >> 3) ^ (row & 7);
          *(u16*)((char*)Ps + w * 4096 + row * 128 + swz * 16 + (col & 7) * 2) =
              __builtin_bit_cast(u16, (__bf16)s[n2][r]);
        }
      }
    }

    // T14 write-late: V prefetch regs -> next buffer
    if (pf) vwrite(Vt[cur ^ 1], va, vb2, vp, vec);

    if (doWork) {
      // PV: D[q][e] = P[q][kv] V[kv][e], 2 n-tiles x 4 k-steps
      __builtin_amdgcn_s_setprio(1);
#pragma unroll
      for (int ks = 0; ks < 4; ks++) {
        int c2 = ks * 2 + half;                          // P 16B chunk (kv/8)
        bf16x8 pa = *(const bf16x8*)((char*)Ps + w * 4096 + l31 * 128 +
                                     ((c2 ^ (l31 & 7)) * 16));
        int kvb = ks * 16 + half * 8;                    // kv base of 8 elems
#pragma unroll
        for (int n2 = 0; n2 < 2; n2++) {
          int e = n2 * 32 + l31;
          int slot = (kvb >> 3) ^ (e & 7) ^ (e >> 3);
          bf16x8 vbf = *(const bf16x8*)((char*)Vt[cur] + e * 128 + slot * 16);
          o[n2] = __builtin_amdgcn_mfma_f32_32x32x16_bf16(pa, vbf, o[n2], 0, 0, 0);
        }
      }
      __builtin_amdgcn_s_setprio(0);
    }
    __syncthreads();
    cur ^= 1;
  }

  // epilogue: reduce lrow across the 32-lane half (cols), normalize, store
#pragma unroll
  for (int r = 0; r < 16; r++) {
    float l = lrow[r];
    l += __shfl_xor(l, 1);
    l += __shfl_xor(l, 2);
    l += __shfl_xor(l, 4);
    l += __shfl_xor(l, 8);
    l += __shfl_xor(l, 16);
    float inv = 1.0f / l;
    int q = wqb + (r & 3) + 8 * (r >> 2) + 4 * half;
#pragma unroll
    for (int n2 = 0; n2 < 2; n2++) {
      int col = h * NE + n2 * 32 + l31;
      out[((size_t)b * S_LEN + q) * (NH * NE) + col] = o[n2][r] * inv;
    }
  }
}

extern "C" void kernel_launch(void* const* d_in, const int* in_sizes, int n_in,
                              void* d_out, int out_size, void* d_ws, size_t ws_size,
                              hipStream_t stream) {
  const float* x = (const float*)d_in[0];
  const float* Wq = (const float*)d_in[1];
  const float* Wk = (const float*)d_in[2];
  const float* Wv = (const float*)d_in[3];
  float* out = (float*)d_out;

  char* ws = (char*)d_ws;
  u16* xb = (u16*)ws;                          // 4096*1024*2  = 8 MB
  u16* Wt = (u16*)(ws + (8u << 20));           // 3072*1024*2  = 6 MB
  u16* qkv = (u16*)(ws + (14u << 20));         // 4096*3072*2  = 24 MB

  k_prep<<<dim3(2816), dim3(256), 0, stream>>>(x, Wq, Wk, Wv, xb, Wt);
  k_gemm<<<dim3(768), dim3(256), 0, stream>>>(xb, Wt, qkv);
  k_attn<<<dim3(512), dim3(256), 0, stream>>>(qkv, out);
}

// Round 11
// 119.281 us; speedup vs baseline: 1.2738x; 1.2738x over previous
//
#include <hip/hip_runtime.h>
#include <stdint.h>

// Problem constants
#define S_LEN 2048
#define D_DIM 1024
#define NB 2
#define NH 16
#define NE 64
#define N_COLS (3 * NH * NE)  // 3072 (Q | K | V column blocks)
#define K_DIM D_DIM           // 1024

typedef unsigned short u16;
typedef unsigned int u32;
typedef u16 u16x8 __attribute__((ext_vector_type(8)));
typedef __bf16 bf16x8 __attribute__((ext_vector_type(8)));
typedef float f32x4 __attribute__((ext_vector_type(4)));

__device__ __forceinline__ u16 f2b(float f) {
  u32 u = __builtin_bit_cast(u32, f);
  return (u16)((u + 0x7FFFu + ((u >> 16) & 1u)) >> 16);  // RNE
}

__device__ __forceinline__ void gload_lds16(const void* g, void* l) {
  __builtin_amdgcn_global_load_lds(
      (const __attribute__((address_space(1))) u32*)g,
      (__attribute__((address_space(3))) u32*)l, 16, 0, 0);
}

// ---------- merged prep: blocks [0,2048) convert x; [2048,2816) transpose W ----------
__global__ __launch_bounds__(256) void k_prep(const float* __restrict__ x,
                                              const float* __restrict__ Wq,
                                              const float* __restrict__ Wk,
                                              const float* __restrict__ Wv,
                                              u16* __restrict__ xb,
                                              u16* __restrict__ Wt) {
  __shared__ u16 tile[64][65];
  int bid = blockIdx.x;
  int t = threadIdx.x;
  if (bid < 2048) {
    size_t i = (size_t)bid * 256 + t;
    const float4* xf = (const float4*)x;
    float4 a = xf[2 * i], c = xf[2 * i + 1];
    u16x8 o;
    o[0] = f2b(a.x); o[1] = f2b(a.y); o[2] = f2b(a.z); o[3] = f2b(a.w);
    o[4] = f2b(c.x); o[5] = f2b(c.y); o[6] = f2b(c.z); o[7] = f2b(c.w);
    *(u16x8*)(xb + 8 * i) = o;
  } else {
    int wbid = bid - 2048;             // proj*256 + h*16 + kb
    int kb = wbid & 15;
    int h = (wbid >> 4) & 15;
    int proj = wbid >> 8;
    const float* W = (proj == 0) ? Wq : ((proj == 1) ? Wk : Wv);
    int k0 = kb * 64;
    int e = t & 63, kr = t >> 6;
    const float* src = W + ((size_t)h * D_DIM + k0 + kr * 16) * NE + e;
#pragma unroll
    for (int j = 0; j < 16; ++j) tile[kr * 16 + j][e] = f2b(src[(size_t)j * NE]);
    __syncthreads();
    int e2 = t >> 2, kc = (t & 3) * 16;
    u16x8 o0, o1;
#pragma unroll
    for (int j = 0; j < 8; ++j) { o0[j] = tile[kc + j][e2]; o1[j] = tile[kc + 8 + j][e2]; }
    size_t n = (size_t)proj * 1024 + h * 64 + e2;
    u16* dst = Wt + n * K_DIM + k0 + kc;
    *(u16x8*)dst = o0;
    *(u16x8*)(dst + 8) = o1;
  }
}

// ------------- GEMM: qkv[4096,3072] = xb[4096,1024] @ Wt[3072,1024]^T -------------
__global__ __launch_bounds__(256) void k_gemm(const u16* __restrict__ A,
                                              const u16* __restrict__ Bt,
                                              u16* __restrict__ C) {
  __shared__ __align__(16) u16 As[128 * 64];
  __shared__ __align__(16) u16 Bs[128 * 64];
  int t = threadIdx.x;
  int lane = t & 63, w = t >> 6;
  int wr = (w >> 1) * 64, wc = (w & 1) * 64;
  int bid = blockIdx.x;
  int xcd = bid & 7, r0 = bid >> 3;          // r0 in [0,96)
  int m0 = (r0 / 3) * 128;
  int n0 = (xcd * 3 + (r0 % 3)) * 128;
  float qscale = ((n0 + wc) < 1024) ? 0.18033688f : 1.0f;  // 0.125*log2e
  f32x4 acc[4][4];
#pragma unroll
  for (int m = 0; m < 4; m++)
#pragma unroll
    for (int n = 0; n < 4; n++)
#pragma unroll
      for (int j = 0; j < 4; j++) acc[m][n][j] = 0.f;

  for (int k0 = 0; k0 < K_DIM; k0 += 64) {
#pragma unroll
    for (int i = 0; i < 4; ++i) {
      int ci = i * 256 + t;
      int row = ci >> 3, c = ci & 7;
      int cs = c ^ (row & 7);
      gload_lds16(A + (size_t)(m0 + row) * K_DIM + k0 + cs * 8,
                  (char*)As + (size_t)(i * 256 + w * 64) * 16);
      gload_lds16(Bt + (size_t)(n0 + row) * K_DIM + k0 + cs * 8,
                  (char*)Bs + (size_t)(i * 256 + w * 64) * 16);
    }
    __syncthreads();
#pragma unroll
    for (int ks = 0; ks < 2; ++ks) {
      int kc = ks * 4 + (lane >> 4);
      bf16x8 af[4], bfr[4];
#pragma unroll
      for (int m = 0; m < 4; m++) {
        int r = wr + m * 16 + (lane & 15);
        af[m] = *(const bf16x8*)&As[r * 64 + ((kc ^ (r & 7)) * 8)];
      }
#pragma unroll
      for (int n = 0; n < 4; n++) {
        int r = wc + n * 16 + (lane & 15);
        bfr[n] = *(const bf16x8*)&Bs[r * 64 + ((kc ^ (r & 7)) * 8)];
      }
#pragma unroll
      for (int m = 0; m < 4; m++)
#pragma unroll
        for (int n = 0; n < 4; n++)
          acc[m][n] = __builtin_amdgcn_mfma_f32_16x16x32_bf16(af[m], bfr[n], acc[m][n], 0, 0, 0);
    }
    __syncthreads();
  }
#pragma unroll
  for (int m = 0; m < 4; m++) {
#pragma unroll
    for (int r = 0; r < 4; r++) {
      int row = m0 + wr + m * 16 + (lane >> 4) * 4 + r;
#pragma unroll
      for (int n = 0; n < 4; n++) {
        int col = n0 + wc + n * 16 + (lane & 15);
        C[(size_t)row * N_COLS + col] = f2b(acc[m][n][r] * qscale);
      }
    }
  }
}

// ---- attention helpers (256-thread block) ----
__device__ __forceinline__ void stage_k(const u16* kb_, u16* kdst, int kv0, int t, int w) {
#pragma unroll
  for (int i = 0; i < 2; ++i) {
    int ci = i * 256 + t;
    int row = ci >> 3, c = ci & 7;
    int cs = c ^ (row & 7);
    gload_lds16(kb_ + (size_t)(kv0 + row) * N_COLS + cs * 8,
                (char*)kdst + (size_t)(i * 256 + w * 64) * 16);  // wave-uniform base
  }
}

// V write: thread covers kv pair vp = t>>3, e-chunk vec = t&7.
// Vt element (e,kv) at byte e*128 + slot*16 + (kv&7)*2, slot=(kv>>3)^(e&7)^(e>>3).
__device__ __forceinline__ void vwrite(u16* vt, u16x8 va, u16x8 vb2, int vp, int vec) {
#pragma unroll
  for (int j = 0; j < 8; ++j) {
    int e = vec * 8 + j;
    int slot = (vp >> 2) ^ (e & 7) ^ (e >> 3);
    *(u32*)((char*)vt + e * 128 + slot * 16 + (vp & 3) * 4) =
        (u32)va[j] | ((u32)vb2[j] << 16);
  }
}

// ----- flash attention, causal, 16x16 MFMA, two 64-row strips share staged K/V -----
// 512 blocks x 4 waves. Decode: xcd=bid&7, g=bid>>3; bh=xcd*4+(g&3) (4 heads' K/V
// = 2 MB per XCD L2); qb=15-(g>>2) (LPT longest-first). Block covers q in
// [qb*128, qb*128+128) as strips A (q0+w*16) and B (A+64). Per kv-tile each K
// fragment register feeds both strips' QK^T MFMAs (K LDS reads halve); staging,
// V-transpose, barrier, bookkeeping amortized 2x. Strip A: mask at ti==nt-2,
// skip post-work at ti==nt-1 (fully masked). Strip B: mask at ti==nt-1.
// No-max exp2 softmax (Q pre-scaled by 0.125*log2e in GEMM).
__global__ __launch_bounds__(256) void k_attn(const u16* __restrict__ qkv,
                                              float* __restrict__ out) {
  __shared__ __align__(16) u16 Ks[2][64 * 64];
  __shared__ __align__(16) u16 Vt[2][64 * 64];
  __shared__ __align__(16) u16 Ps[64 * 64];
  int t = threadIdx.x;
  int lane = t & 63, w = t >> 6;
  int bid = blockIdx.x;                 // 0..511
  int xcd = bid & 7, g = bid >> 3;
  int bh = xcd * 4 + (g & 3);
  int qb = 15 - (g >> 2);
  int b = bh >> 4, h = bh & 15;
  const u16* qb_ = qkv + (size_t)b * S_LEN * N_COLS + h * NE;
  const u16* kb_ = qb_ + 1024;
  const u16* vb_ = qb_ + 2048;
  int vp = t >> 3, vec = t & 7;

  int q0 = qb * 128;
  int nt = 2 * qb + 2;
  int wqbA = q0 + w * 16;               // strip A wave q-base; strip B = +64

  bf16x8 qfA[2], qfB[2];
#pragma unroll
  for (int ks = 0; ks < 2; ks++) {
    qfA[ks] = *(const bf16x8*)(qb_ + (size_t)(wqbA + (lane & 15)) * N_COLS + ks * 32 + (lane >> 4) * 8);
    qfB[ks] = *(const bf16x8*)(qb_ + (size_t)(wqbA + 64 + (lane & 15)) * N_COLS + ks * 32 + (lane >> 4) * 8);
  }

  f32x4 oA[4], oB[4];
  float lA[4], lB[4];
#pragma unroll
  for (int i = 0; i < 4; i++) {
#pragma unroll
    for (int j = 0; j < 4; j++) { oA[i][j] = 0.f; oB[i][j] = 0.f; }
    lA[i] = 0.f; lB[i] = 0.f;
  }
  int myqA = wqbA + (lane >> 4) * 4;    // strip A q for reg r: myqA + r

  // prologue: stage tile 0 into buffer 0
  stage_k(kb_, Ks[0], 0, t, w);
  {
    const u16* vs = vb_ + (size_t)(2 * vp) * N_COLS + vec * 8;
    u16x8 va = *(const u16x8*)vs;
    u16x8 vb2 = *(const u16x8*)(vs + N_COLS);
    vwrite(Vt[0], va, vb2, vp, vec);
  }
  __syncthreads();

  int cur = 0;
  for (int ti = 0; ti < nt; ++ti) {
    int kv0 = ti * 64;
    bool pf = (ti + 1 < nt);
    u16x8 va, vb2;
    if (pf) {
      const u16* vs = vb_ + (size_t)(kv0 + 64 + 2 * vp) * N_COLS + vec * 8;
      va = *(const u16x8*)vs;            // in flight during QK^T+softmax
      vb2 = *(const u16x8*)(vs + N_COLS);
      stage_k(kb_, Ks[cur ^ 1], kv0 + 64, t, w);
    }
    bool doA = (ti != nt - 1);           // last tile fully masked for strip A
    bool maskA = (ti == nt - 2);
    bool maskB = (ti == nt - 1);

    // QK^T both strips: each kf register feeds 2 MFMAs (A wasted on last tile)
    f32x4 sA[4], sB[4];
#pragma unroll
    for (int f = 0; f < 4; f++)
#pragma unroll
      for (int j = 0; j < 4; j++) { sA[f][j] = 0.f; sB[f][j] = 0.f; }
    __builtin_amdgcn_s_setprio(1);
#pragma unroll
    for (int ks = 0; ks < 2; ks++) {
      int kc = ks * 4 + (lane >> 4);
#pragma unroll
      for (int f = 0; f < 4; f++) {
        int r = f * 16 + (lane & 15);
        bf16x8 kf = *(const bf16x8*)&Ks[cur][r * 64 + ((kc ^ (r & 7)) * 8)];
        sA[f] = __builtin_amdgcn_mfma_f32_16x16x32_bf16(qfA[ks], kf, sA[f], 0, 0, 0);
        sB[f] = __builtin_amdgcn_mfma_f32_16x16x32_bf16(qfB[ks], kf, sB[f], 0, 0, 0);
      }
    }
    __builtin_amdgcn_s_setprio(0);

    // ---- strip A post-work ----
    if (doA) {
#pragma unroll
      for (int r = 0; r < 4; ++r) {
#pragma unroll
        for (int f = 0; f < 4; f++) {
          float p = __builtin_amdgcn_exp2f(sA[f][r]);
          if (maskA) {
            int kv = kv0 + f * 16 + (lane & 15);
            p = (kv <= myqA + r) ? p : 0.f;
          }
          sA[f][r] = p;
        }
        lA[r] += (sA[0][r] + sA[1][r]) + (sA[2][r] + sA[3][r]);
      }
#pragma unroll
      for (int f = 0; f < 4; f++) {
#pragma unroll
        for (int r = 0; r < 4; r++) {
          int row = w * 16 + (lane >> 4) * 4 + r;
          int col = f * 16 + (lane & 15);
          int swz = (col >> 3) ^ (row & 7);
          *(u16*)((char*)Ps + row * 128 + swz * 16 + (col & 7) * 2) =
              __builtin_bit_cast(u16, (__bf16)sA[f][r]);
        }
      }
      if (pf) vwrite(Vt[cur ^ 1], va, vb2, vp, vec);  // T14 write-late
      __builtin_amdgcn_s_setprio(1);
#pragma unroll
      for (int ks = 0; ks < 2; ks++) {
        int kc = ks * 4 + (lane >> 4);
        int pr = w * 16 + (lane & 15);
        bf16x8 pa = *(const bf16x8*)&Ps[pr * 64 + ((kc ^ (pr & 7)) * 8)];
#pragma unroll
        for (int ef = 0; ef < 4; ef++) {
          int vr = ef * 16 + (lane & 15);
          int vswz = kc ^ (vr & 7) ^ (vr >> 3);
          bf16x8 vbf = *(const bf16x8*)&Vt[cur][vr * 64 + vswz * 8];
          oA[ef] = __builtin_amdgcn_mfma_f32_16x16x32_bf16(pa, vbf, oA[ef], 0, 0, 0);
        }
      }
      __builtin_amdgcn_s_setprio(0);
    } else if (pf) {
      vwrite(Vt[cur ^ 1], va, vb2, vp, vec);
    }

    // ---- strip B post-work (Ps reuse safe: PV-A MFMAs consumed the reads) ----
#pragma unroll
    for (int r = 0; r < 4; ++r) {
#pragma unroll
      for (int f = 0; f < 4; f++) {
        float p = __builtin_amdgcn_exp2f(sB[f][r]);
        if (maskB) {
          int kv = kv0 + f * 16 + (lane & 15);
          p = (kv <= myqA + 64 + r) ? p : 0.f;
        }
        sB[f][r] = p;
      }
      lB[r] += (sB[0][r] + sB[1][r]) + (sB[2][r] + sB[3][r]);
    }
#pragma unroll
    for (int f = 0; f < 4; f++) {
#pragma unroll
      for (int r = 0; r < 4; r++) {
        int row = w * 16 + (lane >> 4) * 4 + r;
        int col = f * 16 + (lane & 15);
        int swz = (col >> 3) ^ (row & 7);
        *(u16*)((char*)Ps + row * 128 + swz * 16 + (col & 7) * 2) =
            __builtin_bit_cast(u16, (__bf16)sB[f][r]);
      }
    }
    __builtin_amdgcn_s_setprio(1);
#pragma unroll
    for (int ks = 0; ks < 2; ks++) {
      int kc = ks * 4 + (lane >> 4);
      int pr = w * 16 + (lane & 15);
      bf16x8 pa = *(const bf16x8*)&Ps[pr * 64 + ((kc ^ (pr & 7)) * 8)];
#pragma unroll
      for (int ef = 0; ef < 4; ef++) {
        int vr = ef * 16 + (lane & 15);
        int vswz = kc ^ (vr & 7) ^ (vr >> 3);
        bf16x8 vbf = *(const bf16x8*)&Vt[cur][vr * 64 + vswz * 8];
        oB[ef] = __builtin_amdgcn_mfma_f32_16x16x32_bf16(pa, vbf, oB[ef], 0, 0, 0);
      }
    }
    __builtin_amdgcn_s_setprio(0);
    __syncthreads();
    cur ^= 1;
  }

  // epilogue: reduce l across the 16-lane col groups, normalize, store both strips
#pragma unroll
  for (int r = 0; r < 4; r++) {
    float la = lA[r], lb = lB[r];
    la += __shfl_xor(la, 1); lb += __shfl_xor(lb, 1);
    la += __shfl_xor(la, 2); lb += __shfl_xor(lb, 2);
    la += __shfl_xor(la, 4); lb += __shfl_xor(lb, 4);
    la += __shfl_xor(la, 8); lb += __shfl_xor(lb, 8);
    float invA = 1.0f / la, invB = 1.0f / lb;
    int qA = myqA + r;
#pragma unroll
    for (int ef = 0; ef < 4; ef++) {
      int col = h * NE + ef * 16 + (lane & 15);
      size_t base = (size_t)b * S_LEN;
      out[(base + qA) * (NH * NE) + col] = oA[ef][r] * invA;
      out[(base + qA + 64) * (NH * NE) + col] = oB[ef][r] * invB;
    }
  }
}

extern "C" void kernel_launch(void* const* d_in, const int* in_sizes, int n_in,
                              void* d_out, int out_size, void* d_ws, size_t ws_size,
                              hipStream_t stream) {
  const float* x = (const float*)d_in[0];
  const float* Wq = (const float*)d_in[1];
  const float* Wk = (const float*)d_in[2];
  const float* Wv = (const float*)d_in[3];
  float* out = (float*)d_out;

  char* ws = (char*)d_ws;
  u16* xb = (u16*)ws;                          // 4096*1024*2  = 8 MB
  u16* Wt = (u16*)(ws + (8u << 20));           // 3072*1024*2  = 6 MB
  u16* qkv = (u16*)(ws + (14u << 20));         // 4096*3072*2  = 24 MB

  k_prep<<<dim3(2816), dim3(256), 0, stream>>>(x, Wq, Wk, Wv, xb, Wt);
  k_gemm<<<dim3(768), dim3(256), 0, stream>>>(xb, Wt, qkv);
  k_attn<<<dim3(512), dim3(256), 0, stream>>>(qkv, out);
}

// Round 12
// 93.924 us; speedup vs baseline: 1.6177x; 1.2700x over previous
//
#include <hip/hip_runtime.h>
#include <stdint.h>

// Problem constants
#define S_LEN 2048
#define D_DIM 1024
#define NB 2
#define NH 16
#define NE 64
#define N_COLS (3 * NH * NE)  // 3072 (Q | K | V column blocks)
#define K_DIM D_DIM           // 1024

typedef unsigned short u16;
typedef unsigned int u32;
typedef u16 u16x8 __attribute__((ext_vector_type(8)));
typedef __bf16 bf16x8 __attribute__((ext_vector_type(8)));
typedef __bf16 bf16x4 __attribute__((ext_vector_type(4)));
typedef float f32x4 __attribute__((ext_vector_type(4)));

__device__ __forceinline__ u16 f2b(float f) {
  u32 u = __builtin_bit_cast(u32, f);
  return (u16)((u + 0x7FFFu + ((u >> 16) & 1u)) >> 16);  // RNE
}

__device__ __forceinline__ void gload_lds16(const void* g, void* l) {
  __builtin_amdgcn_global_load_lds(
      (const __attribute__((address_space(1))) u32*)g,
      (__attribute__((address_space(3))) u32*)l, 16, 0, 0);
}

// ---------- merged prep: blocks [0,2048) convert x; [2048,2816) transpose W ----------
__global__ __launch_bounds__(256) void k_prep(const float* __restrict__ x,
                                              const float* __restrict__ Wq,
                                              const float* __restrict__ Wk,
                                              const float* __restrict__ Wv,
                                              u16* __restrict__ xb,
                                              u16* __restrict__ Wt) {
  __shared__ u16 tile[64][65];
  int bid = blockIdx.x;
  int t = threadIdx.x;
  if (bid < 2048) {
    size_t i = (size_t)bid * 256 + t;
    const float4* xf = (const float4*)x;
    float4 a = xf[2 * i], c = xf[2 * i + 1];
    u16x8 o;
    o[0] = f2b(a.x); o[1] = f2b(a.y); o[2] = f2b(a.z); o[3] = f2b(a.w);
    o[4] = f2b(c.x); o[5] = f2b(c.y); o[6] = f2b(c.z); o[7] = f2b(c.w);
    *(u16x8*)(xb + 8 * i) = o;
  } else {
    int wbid = bid - 2048;             // proj*256 + h*16 + kb
    int kb = wbid & 15;
    int h = (wbid >> 4) & 15;
    int proj = wbid >> 8;
    const float* W = (proj == 0) ? Wq : ((proj == 1) ? Wk : Wv);
    int k0 = kb * 64;
    int e = t & 63, kr = t >> 6;
    const float* src = W + ((size_t)h * D_DIM + k0 + kr * 16) * NE + e;
#pragma unroll
    for (int j = 0; j < 16; ++j) tile[kr * 16 + j][e] = f2b(src[(size_t)j * NE]);
    __syncthreads();
    int e2 = t >> 2, kc = (t & 3) * 16;
    u16x8 o0, o1;
#pragma unroll
    for (int j = 0; j < 8; ++j) { o0[j] = tile[kc + j][e2]; o1[j] = tile[kc + 8 + j][e2]; }
    size_t n = (size_t)proj * 1024 + h * 64 + e2;
    u16* dst = Wt + n * K_DIM + k0 + kc;
    *(u16x8*)dst = o0;
    *(u16x8*)(dst + 8) = o1;
  }
}

// ------------- GEMM: qkv[4096,3072] = xb[4096,1024] @ Wt[3072,1024]^T -------------
__global__ __launch_bounds__(256) void k_gemm(const u16* __restrict__ A,
                                              const u16* __restrict__ Bt,
                                              u16* __restrict__ C) {
  __shared__ __align__(16) u16 As[128 * 64];
  __shared__ __align__(16) u16 Bs[128 * 64];
  int t = threadIdx.x;
  int lane = t & 63, w = t >> 6;
  int wr = (w >> 1) * 64, wc = (w & 1) * 64;
  int bid = blockIdx.x;
  int xcd = bid & 7, r0 = bid >> 3;          // r0 in [0,96)
  int m0 = (r0 / 3) * 128;
  int n0 = (xcd * 3 + (r0 % 3)) * 128;
  float qscale = ((n0 + wc) < 1024) ? 0.18033688f : 1.0f;  // 0.125*log2e
  f32x4 acc[4][4];
#pragma unroll
  for (int m = 0; m < 4; m++)
#pragma unroll
    for (int n = 0; n < 4; n++)
#pragma unroll
      for (int j = 0; j < 4; j++) acc[m][n][j] = 0.f;

  for (int k0 = 0; k0 < K_DIM; k0 += 64) {
#pragma unroll
    for (int i = 0; i < 4; ++i) {
      int ci = i * 256 + t;
      int row = ci >> 3, c = ci & 7;
      int cs = c ^ (row & 7);
      gload_lds16(A + (size_t)(m0 + row) * K_DIM + k0 + cs * 8,
                  (char*)As + (size_t)(i * 256 + w * 64) * 16);
      gload_lds16(Bt + (size_t)(n0 + row) * K_DIM + k0 + cs * 8,
                  (char*)Bs + (size_t)(i * 256 + w * 64) * 16);
    }
    __syncthreads();
#pragma unroll
    for (int ks = 0; ks < 2; ++ks) {
      int kc = ks * 4 + (lane >> 4);
      bf16x8 af[4], bfr[4];
#pragma unroll
      for (int m = 0; m < 4; m++) {
        int r = wr + m * 16 + (lane & 15);
        af[m] = *(const bf16x8*)&As[r * 64 + ((kc ^ (r & 7)) * 8)];
      }
#pragma unroll
      for (int n = 0; n < 4; n++) {
        int r = wc + n * 16 + (lane & 15);
        bfr[n] = *(const bf16x8*)&Bs[r * 64 + ((kc ^ (r & 7)) * 8)];
      }
#pragma unroll
      for (int m = 0; m < 4; m++)
#pragma unroll
        for (int n = 0; n < 4; n++)
          acc[m][n] = __builtin_amdgcn_mfma_f32_16x16x32_bf16(af[m], bfr[n], acc[m][n], 0, 0, 0);
    }
    __syncthreads();
  }
#pragma unroll
  for (int m = 0; m < 4; m++) {
#pragma unroll
    for (int r = 0; r < 4; r++) {
      int row = m0 + wr + m * 16 + (lane >> 4) * 4 + r;
#pragma unroll
      for (int n = 0; n < 4; n++) {
        int col = n0 + wc + n * 16 + (lane & 15);
        C[(size_t)row * N_COLS + col] = f2b(acc[m][n][r] * qscale);
      }
    }
  }
}

// ---- attention helpers (256-thread block) ----
__device__ __forceinline__ void stage_k(const u16* kb_, u16* kdst, int kv0, int t, int w) {
#pragma unroll
  for (int i = 0; i < 2; ++i) {
    int ci = i * 256 + t;
    int row = ci >> 3, c = ci & 7;
    int cs = c ^ (row & 7);
    gload_lds16(kb_ + (size_t)(kv0 + row) * N_COLS + cs * 8,
                (char*)kdst + (size_t)(i * 256 + w * 64) * 16);  // wave-uniform base
  }
}

// V write: thread covers kv pair vp = t>>3, e-chunk vec = t&7.
// Vt element (e,kv) at byte e*128 + slot*16 + (kv&7)*2, slot=(kv>>3)^(e&7)^(e>>3).
__device__ __forceinline__ void vwrite(u16* vt, u16x8 va, u16x8 vb2, int vp, int vec) {
#pragma unroll
  for (int j = 0; j < 8; ++j) {
    int e = vec * 8 + j;
    int slot = (vp >> 2) ^ (e & 7) ^ (e >> 3);
    *(u32*)((char*)vt + e * 128 + slot * 16 + (vp & 3) * 4) =
        (u32)va[j] | ((u32)vb2[j] << 16);
  }
}

// ------- flash attention, causal, swapped-QK^T, register-P (no P LDS roundtrip) -------
// 1024 blocks x 4 waves (round-6 structure: x=bid&7, g=bid>>3, bh=x*4+(g&3),
// qt=31-(g>>2), LPT+XCD). Wave owns 16 q rows. QK^T computed as mfma(K,Q)
// (operands swapped; same fragment loads): lane then holds P[kv=kv0+16f+4*hi+r]
// [q=wqb+(lane&15)] - so PV's A-operand 8-elem k-slots are REGISTER-LOCAL
// (k-slot (hi,j): j<4 -> kv=32ks+4hi+j, j>=4 -> kv=32ks+16+4hi+j-4). V B-operand
// reads the SAME k-permutation from swizzled Vt as two b64 chunks (within-MFMA
// K-permutation cancels when A and B agree). No Ps buffer; LDS 32 KB.
// No-max exp2 softmax (Q pre-scaled by 0.125*log2e in GEMM); per-lane scalar lsum.
__global__ __launch_bounds__(256) void k_attn(const u16* __restrict__ qkv,
                                              float* __restrict__ out) {
  __shared__ __align__(16) u16 Ks[2][64 * 64];
  __shared__ __align__(16) u16 Vt[2][64 * 64];
  int t = threadIdx.x;
  int lane = t & 63, w = t >> 6;
  int hi = lane >> 4, l15 = lane & 15;
  int bid = blockIdx.x;                 // 0..1023
  int x = bid & 7, g = bid >> 3;
  int bh = x * 4 + (g & 3);
  int qt = 31 - (g >> 2);
  int b = bh >> 4, h = bh & 15;
  const u16* qb_ = qkv + (size_t)b * S_LEN * N_COLS + h * NE;
  const u16* kb_ = qb_ + 1024;
  const u16* vb_ = qb_ + 2048;
  int vp = t >> 3, vec = t & 7;

  int q0 = qt * 64;
  int nt = qt + 1;
  int wqb = q0 + w * 16;                // wave q base; lane q = wqb + l15

  bf16x8 qf[2];
#pragma unroll
  for (int ks = 0; ks < 2; ks++)
    qf[ks] = *(const bf16x8*)(qb_ + (size_t)(wqb + l15) * N_COLS + ks * 32 + hi * 8);

  f32x4 o[4];
#pragma unroll
  for (int i = 0; i < 4; i++)
#pragma unroll
    for (int j = 0; j < 4; j++) o[i][j] = 0.f;
  float lsum = 0.f;
  int myq = wqb + l15;

  // prologue: stage tile 0 into buffer 0
  stage_k(kb_, Ks[0], 0, t, w);
  {
    const u16* vs = vb_ + (size_t)(2 * vp) * N_COLS + vec * 8;
    u16x8 va = *(const u16x8*)vs;
    u16x8 vb2 = *(const u16x8*)(vs + N_COLS);
    vwrite(Vt[0], va, vb2, vp, vec);
  }
  __syncthreads();

  int cur = 0;
  for (int ti = 0; ti < nt; ++ti) {
    int kv0 = ti * 64;
    bool pf = (ti + 1 < nt);
    u16x8 va, vb2;
    if (pf) {
      const u16* vs = vb_ + (size_t)(kv0 + 64 + 2 * vp) * N_COLS + vec * 8;
      va = *(const u16x8*)vs;            // in flight during QK^T+softmax
      vb2 = *(const u16x8*)(vs + N_COLS);
      stage_k(kb_, Ks[cur ^ 1], kv0 + 64, t, w);
    }

    // S^T = K Q : s[f][r] = S[kv = kv0+16f+4hi+r][q = myq]
    f32x4 s[4];
#pragma unroll
    for (int f = 0; f < 4; f++)
#pragma unroll
      for (int j = 0; j < 4; j++) s[f][j] = 0.f;
    __builtin_amdgcn_s_setprio(1);
#pragma unroll
    for (int ks = 0; ks < 2; ks++) {
      int kc = ks * 4 + hi;
#pragma unroll
      for (int f = 0; f < 4; f++) {
        int r = f * 16 + l15;
        bf16x8 kf = *(const bf16x8*)&Ks[cur][r * 64 + ((kc ^ (r & 7)) * 8)];
        s[f] = __builtin_amdgcn_mfma_f32_16x16x32_bf16(kf, qf[ks], s[f], 0, 0, 0);
      }
    }
    __builtin_amdgcn_s_setprio(0);

    // no-max softmax: p = exp2(s); mask last tile per-element; lsum per-lane (q fixed)
    bool diag = (ti == nt - 1);
#pragma unroll
    for (int f = 0; f < 4; f++) {
#pragma unroll
      for (int r = 0; r < 4; r++) {
        float p = __builtin_amdgcn_exp2f(s[f][r]);
        if (diag) {
          int kv = kv0 + f * 16 + 4 * hi + r;
          p = (kv <= myq) ? p : 0.f;
        }
        s[f][r] = p;
        lsum += p;
      }
    }

    // T14 write-late: V prefetch regs -> next buffer
    if (pf) vwrite(Vt[cur ^ 1], va, vb2, vp, vec);

    // PV: pa register-local; V read with the matching k-permutation (2 x b64)
    __builtin_amdgcn_s_setprio(1);
#pragma unroll
    for (int ks = 0; ks < 2; ks++) {
      bf16x8 pa;
#pragma unroll
      for (int j = 0; j < 4; j++) {
        pa[j] = (__bf16)s[2 * ks][j];
        pa[4 + j] = (__bf16)s[2 * ks + 1][j];
      }
      int kvo1 = 32 * ks + 4 * hi;       // j<4  -> kv = kvo1 + j
      int kvo2 = kvo1 + 16;              // j>=4 -> kv = kvo2 + (j-4)
#pragma unroll
      for (int ef = 0; ef < 4; ef++) {
        int e = ef * 16 + l15;
        int sw = (e & 7) ^ (e >> 3);
        int a1 = e * 128 + (((kvo1 >> 3) ^ sw) * 16) + (kvo1 & 7) * 2;
        int a2 = e * 128 + (((kvo2 >> 3) ^ sw) * 16) + (kvo2 & 7) * 2;
        bf16x4 vlo = *(const bf16x4*)((const char*)Vt[cur] + a1);
        bf16x4 vhi = *(const bf16x4*)((const char*)Vt[cur] + a2);
        bf16x8 vbf;
#pragma unroll
        for (int j = 0; j < 4; j++) { vbf[j] = vlo[j]; vbf[4 + j] = vhi[j]; }
        o[ef] = __builtin_amdgcn_mfma_f32_16x16x32_bf16(pa, vbf, o[ef], 0, 0, 0);
      }
    }
    __builtin_amdgcn_s_setprio(0);
    __syncthreads();
    cur ^= 1;
  }

  // epilogue: complete row-sum across hi groups, redistribute, normalize, store.
  // lsum holds partial for q = myq; full sum = reduce over lanes {q, q+16, q+32, q+48}.
  lsum += __shfl_xor(lsum, 16);
  lsum += __shfl_xor(lsum, 32);
  // o[ef][r] is O[q = wqb + 4*hi + r][e = ef*16 + l15]
#pragma unroll
  for (int r = 0; r < 4; r++) {
    float l = __shfl(lsum, 4 * hi + r);  // lane 4hi+r holds sum for q = wqb+4hi+r
    float inv = 1.0f / l;
    int q = wqb + 4 * hi + r;
#pragma unroll
    for (int ef = 0; ef < 4; ef++) {
      int col = h * NE + ef * 16 + l15;
      out[((size_t)b * S_LEN + q) * (NH * NE) + col] = o[ef][r] * inv;
    }
  }
}

extern "C" void kernel_launch(void* const* d_in, const int* in_sizes, int n_in,
                              void* d_out, int out_size, void* d_ws, size_t ws_size,
                              hipStream_t stream) {
  const float* x = (const float*)d_in[0];
  const float* Wq = (const float*)d_in[1];
  const float* Wk = (const float*)d_in[2];
  const float* Wv = (const float*)d_in[3];
  float* out = (float*)d_out;

  char* ws = (char*)d_ws;
  u16* xb = (u16*)ws;                          // 4096*1024*2  = 8 MB
  u16* Wt = (u16*)(ws + (8u << 20));           // 3072*1024*2  = 6 MB
  u16* qkv = (u16*)(ws + (14u << 20));         // 4096*3072*2  = 24 MB

  k_prep<<<dim3(2816), dim3(256), 0, stream>>>(x, Wq, Wk, Wv, xb, Wt);
  k_gemm<<<dim3(768), dim3(256), 0, stream>>>(xb, Wt, qkv);
  k_attn<<<dim3(1024), dim3(256), 0, stream>>>(qkv, out);
}